// Round 9
// baseline (418.847 us; speedup 1.0000x reference)
//
#include <hip/hip_runtime.h>
#include <hip/hip_fp16.h>

#define NEG_SLOPE 0.2f
#define LOG2E 1.4426950408889634f

typedef _Float16 half4v __attribute__((ext_vector_type(4)));
typedef _Float16 half8v __attribute__((ext_vector_type(8)));
typedef float f32x4 __attribute__((ext_vector_type(4)));

// ---------------------------------------------------------------------------
// float<->ordered-uint encoding for atomicMax on floats
// ---------------------------------------------------------------------------
__device__ inline unsigned enc_max(float f) {
    unsigned b = __float_as_uint(f);
    return (b & 0x80000000u) ? ~b : (b | 0x80000000u);
}
__device__ inline float dec_max(unsigned k) {
    return (k & 0x80000000u) ? __uint_as_float(k ^ 0x80000000u)
                             : __uint_as_float(~k);
}

// ---------------------------------------------------------------------------
// MFMA GEMM + attention projections.
//   H16[r,:] = fp16(X[r,:] @ W); AL[r] = (als_h0, als_h1, ald_h0, ald_h1)
// AL is PRE-SCALED by log2(e): aggregate uses exp2 (softmax invariant).
// Block = 256 thr = 4 waves, 64 rows. X and W^T staged as fp16 in LDS with a
// (k8 ^ row&7) 16B-slot XOR swizzle. v_mfma_f32_16x16x16f16, 8 col-tiles.
// Epilogue: AL + ub in-register; D -> LDS -> coalesced fp16 write.
// ---------------------------------------------------------------------------
__global__ __launch_bounds__(256) void gemm_al_kernel(
    const float* __restrict__ X, const float* __restrict__ W,
    const float* __restrict__ asrc, const float* __restrict__ adst,
    __half* __restrict__ H16, float* __restrict__ AL,
    unsigned* __restrict__ ubp, int N)
{
    __shared__ alignas(16) char smem[49152];

    const int t = threadIdx.x, lane = t & 63, wave = t >> 6;
    const int r0 = blockIdx.x * 64;

    // ---- stage X (fp32 -> fp16, swizzled 16B slots) ----
#pragma unroll
    for (int i = 0; i < 8; i++) {
        const int f = t + i * 256;            // 2048 float4 chunks
        const int row = f >> 5, k4 = f & 31;
        const int k8 = k4 >> 1, hf = k4 & 1;
        float4 v = make_float4(0.f, 0.f, 0.f, 0.f);
        if (r0 + row < N) v = ((const float4*)X)[(size_t)(r0 + row) * 32 + k4];
        half4v h = { (_Float16)v.x, (_Float16)v.y, (_Float16)v.z, (_Float16)v.w };
        const int slot = row * 16 + (k8 ^ (row & 7));
        *(half4v*)(smem + slot * 16 + hf * 8) = h;
    }
    // ---- stage W^T (fp32 -> fp16, swizzled) ----
    {
        const int c = t >> 1, kh = t & 1;
        const float* Wc = W + c;              // W[k][c], stride 128
#pragma unroll
        for (int i8 = 0; i8 < 8; i8++) {
            const int k0 = kh * 64 + i8 * 8;
            half8v h;
#pragma unroll
            for (int j = 0; j < 8; j++) h[j] = (_Float16)Wc[(size_t)(k0 + j) * 128];
            const int slot = c * 16 + ((k0 >> 3) ^ (c & 7));
            *(half8v*)(smem + 16384 + slot * 16) = h;
        }
    }
    __syncthreads();

    // ---- MFMA ----
    const int mrow = wave * 16 + (lane & 15);   // local row for A
    const int kg = lane >> 4;                   // k-group 0..3
    half4v a[8];
#pragma unroll
    for (int ks = 0; ks < 8; ks++) {
        const int k0 = ks * 16 + kg * 4;
        const int slot = mrow * 16 + ((k0 >> 3) ^ (mrow & 7));
        a[ks] = *(const half4v*)(smem + slot * 16 + (k0 & 7) * 2);
    }
    f32x4 acc[8];
#pragma unroll
    for (int ct = 0; ct < 8; ct++) acc[ct] = (f32x4){0.f, 0.f, 0.f, 0.f};
#pragma unroll
    for (int ct = 0; ct < 8; ct++) {
        const int c = ct * 16 + (lane & 15);
        const char* sbase = smem + 16384 + c * 256;
        const int csw = c & 7;
#pragma unroll
        for (int ks = 0; ks < 8; ks++) {
            const int k0 = ks * 16 + kg * 4;
            const int slot = (k0 >> 3) ^ csw;
            half4v b = *(const half4v*)(sbase + slot * 16 + (k0 & 7) * 2);
            acc[ct] = __builtin_amdgcn_mfma_f32_16x16x16f16(a[ks], b, acc[ct], 0, 0, 0);
        }
    }

    // ---- AL projections (pre-scaled by log2e) + per-head max ----
    float psh0[4] = {0,0,0,0}, psh1[4] = {0,0,0,0};
    float pdh0[4] = {0,0,0,0}, pdh1[4] = {0,0,0,0};
#pragma unroll
    for (int ct = 0; ct < 8; ct++) {
        const int c = ct * 16 + (lane & 15);
        const float as = asrc[c] * LOG2E, ad = adst[c] * LOG2E;
#pragma unroll
        for (int r = 0; r < 4; r++) {
            if (ct < 4) { psh0[r] = fmaf(acc[ct][r], as, psh0[r]);
                          pdh0[r] = fmaf(acc[ct][r], ad, pdh0[r]); }
            else        { psh1[r] = fmaf(acc[ct][r], as, psh1[r]);
                          pdh1[r] = fmaf(acc[ct][r], ad, pdh1[r]); }
        }
    }
#pragma unroll
    for (int off = 1; off <= 8; off <<= 1) {
#pragma unroll
        for (int r = 0; r < 4; r++) {
            psh0[r] += __shfl_xor(psh0[r], off, 64);
            psh1[r] += __shfl_xor(psh1[r], off, 64);
            pdh0[r] += __shfl_xor(pdh0[r], off, 64);
            pdh1[r] += __shfl_xor(pdh1[r], off, 64);
        }
    }
    float rmax0 = -__builtin_inff(), rmax1 = -__builtin_inff();
    if ((lane & 15) == 0) {
#pragma unroll
        for (int r = 0; r < 4; r++) {
            const int gr = r0 + wave * 16 + (lane >> 4) * 4 + r;
            if (gr < N) {
                ((float4*)AL)[gr] = make_float4(psh0[r], psh1[r], pdh0[r], pdh1[r]);
                rmax0 = fmaxf(rmax0, psh0[r]);
                rmax1 = fmaxf(rmax1, psh1[r]);
            }
        }
    }
#pragma unroll
    for (int off = 32; off > 0; off >>= 1) {
        rmax0 = fmaxf(rmax0, __shfl_xor(rmax0, off, 64));
        rmax1 = fmaxf(rmax1, __shfl_xor(rmax1, off, 64));
    }

    // ---- D -> LDS (reuse staging), then coalesced fp16 write ----
    __syncthreads();
    float* Dst = (float*)smem;
    float* red = (float*)(smem + 33792);
    if (lane == 0) { red[wave * 2] = rmax0; red[wave * 2 + 1] = rmax1; }
#pragma unroll
    for (int ct = 0; ct < 8; ct++) {
        const int col = ct * 16 + (lane & 15);
        float* drow = Dst + wave * 2112 + ((lane >> 4) * 4) * 132 + col;
#pragma unroll
        for (int r = 0; r < 4; r++) drow[r * 132] = acc[ct][r];
    }
    __syncthreads();
    if (t < 2) {
        float m = fmaxf(fmaxf(red[t], red[2 + t]), fmaxf(red[4 + t], red[6 + t]));
        atomicMax(&ubp[t], enc_max(m));
    }
#pragma unroll
    for (int i = 0; i < 4; i++) {
        const int f = t + i * 256;            // 1024 chunks of 8 cols
        const int row = f >> 4, c16 = f & 15;
        if (r0 + row < N) {
            const float* src = Dst + (row >> 4) * 2112 + (row & 15) * 132 + c16 * 8;
            const float4 v0 = *(const float4*)src;
            const float4 v1 = *(const float4*)(src + 4);
            half8v h = { (_Float16)v0.x, (_Float16)v0.y, (_Float16)v0.z, (_Float16)v0.w,
                         (_Float16)v1.x, (_Float16)v1.y, (_Float16)v1.z, (_Float16)v1.w };
            *(half8v*)((_Float16*)H16 + (size_t)(r0 + row) * 128 + c16 * 8) = h;
        }
    }
}

// ---------------------------------------------------------------------------
// Plain per-dst CSR build (count -> scan -> sliced scatter). Self-loops added.
// ---------------------------------------------------------------------------
__global__ void count_kernel(const int* __restrict__ edst, int* __restrict__ cnt,
                             int E, int N)
{
    int i = blockIdx.x * 256 + threadIdx.x;
    if (i < E)            atomicAdd(&cnt[edst[i]], 1);
    else if (i < E + N)   atomicAdd(&cnt[i - E], 1);   // self loop
}

__global__ void scan_local_kernel(const int* __restrict__ in, int* __restrict__ out,
                                  int* __restrict__ bsum, int n)
{
    __shared__ int sm[1024];
    const int t = threadIdx.x;
    const int i = blockIdx.x * 1024 + t;
    int v = (i < n) ? in[i] : 0;
    sm[t] = v;
    __syncthreads();
    for (int off = 1; off < 1024; off <<= 1) {
        int x = (t >= off) ? sm[t - off] : 0;
        __syncthreads();
        sm[t] += x;
        __syncthreads();
    }
    if (i < n) out[i] = sm[t];
    if (t == 1023) bsum[blockIdx.x] = sm[t];
}

__global__ void scan_excl_single_kernel(int* __restrict__ a, int B)
{
    __shared__ int sm[1024];
    const int t = threadIdx.x;
    int v = (t < B) ? a[t] : 0;
    sm[t] = v;
    __syncthreads();
    for (int off = 1; off < 1024; off <<= 1) {
        int x = (t >= off) ? sm[t - off] : 0;
        __syncthreads();
        sm[t] += x;
        __syncthreads();
    }
    if (t < B) a[t] = sm[t] - v;   // exclusive
}

__global__ void finalize_csr_kernel(const int* __restrict__ incl,
                                    const int* __restrict__ cnt,
                                    const int* __restrict__ bexcl,
                                    int* __restrict__ dstptr, int* __restrict__ cursor,
                                    int N, int Etot)
{
    const int i = blockIdx.x * 1024 + threadIdx.x;
    if (i < N) {
        int v = incl[i] + bexcl[i >> 10] - cnt[i];
        dstptr[i] = v;
        cursor[i] = v;
    }
    if (i == N) dstptr[N] = Etot;
}

// Sliced scatter: blocks with blockIdx%8==s handle dst slice s (-> one XCD by
// round-robin dispatch), so each ssrc cache line is written by one XCD only.
__global__ void scatter_kernel(const int* __restrict__ esrc, const int* __restrict__ edst,
                               int* __restrict__ cursor, int* __restrict__ ssrc,
                               int E, int N, int sliceN, int bps)
{
    const int slice = blockIdx.x & 7;
    const int dlo = slice * sliceN;
    const int dhi = min(N, dlo + sliceN);
    const int Etot = E + N;
    for (int i = (blockIdx.x >> 3) * 256 + (int)threadIdx.x; i < Etot; i += bps * 256) {
        int s, d;
        if (i < E) { s = esrc[i]; d = edst[i]; }
        else       { s = d = i - E; }
        if (d >= dlo && d < dhi) {
            int pos = atomicAdd(&cursor[d], 1);
            ssrc[pos] = s;
        }
    }
}

// ---------------------------------------------------------------------------
// Aggregation, shifted softmax in exp2 domain. FOUR nodes per 64-lane wave:
// 16 lanes/node, lane owns 8 channels (uint4 = 16B gathers); head = nl>>3.
// Mov-free 3-slot ring pipeline over 4-edge blocks; unified mask
// rem = edges - 4t covers tail, trip-overflow, and inactive groups.
// mode 0: out[n,128] = ELU(acc/s + b)   mode 1: out[n,64] = mean_h(acc/s)+b
// ---------------------------------------------------------------------------
__global__ __launch_bounds__(256) void aggregate_kernel(
    const __half* __restrict__ H16, const float* __restrict__ AL,
    const int* __restrict__ dstptr, const int* __restrict__ ssrc,
    const unsigned* __restrict__ ubenc, const float* __restrict__ bias,
    float* __restrict__ out, int N, int mode)
{
    const int wid  = (blockIdx.x * blockDim.x + threadIdx.x) >> 6;
    const int lane = threadIdx.x & 63;
    if (wid * 4 >= N) return;
    const int nl   = lane & 15;               // lane within node group
    const int n    = wid * 4 + (lane >> 4);
    const bool act = (n < N);
    const int nn   = act ? n : (N - 1);
    const int beg  = dstptr[nn];
    const int edges = act ? (dstptr[nn + 1] - beg) : 0;

    const int head = nl >> 3;
    const float ald = AL[(size_t)nn * 4 + 2 + head];
    float ub = dec_max(ubenc[head]) + ald;
    ub = fmaxf(ub, NEG_SLOPE * ub);           // leaky, scale-invariant

    int tr = (edges + 3) >> 2;
    tr = max(tr, __shfl_xor(tr, 16, 64));
    tr = max(tr, __shfl_xor(tr, 32, 64));
    const int trips = tr;

    float s = 0.f;
    float a0 = 0.f, a1 = 0.f, a2 = 0.f, a3 = 0.f;
    float a4 = 0.f, a5 = 0.f, a6 = 0.f, a7 = 0.f;

    int   sv0[4], sv1[4], sv2[4];
    float e0[4], e1[4], e2[4];
    uint4 g0[4], g1[4], g2[4];

    auto LSRC = [&](int b, int (&sv)[4]) {
#pragma unroll
        for (int k = 0; k < 4; k++) sv[k] = ssrc[beg + 4 * b + k];  // padded: safe
    };
    auto LHE = [&](const int (&sv)[4], float (&e)[4], uint4 (&g)[4]) {
#pragma unroll
        for (int k = 0; k < 4; k++) {
            e[k] = AL[(size_t)sv[k] * 4 + head];
            g[k] = ((const uint4*)(H16 + (size_t)sv[k] * 128))[nl];
        }
    };
    auto COMP = [&](int t, const float (&e)[4], const uint4 (&g)[4]) {
        const int rem = edges - 4 * t;        // <=0 for overflow/inactive
#pragma unroll
        for (int k = 0; k < 4; k++) {
            float tt = e[k] + ald;
            tt = fmaxf(tt, NEG_SLOPE * tt);   // leaky (logits pre-scaled)
            float p = exp2f(tt - ub);
            p = (k < rem) ? p : 0.f;          // unified mask
            s += p;
            const __half2* ph = (const __half2*)&g[k];
            const float2 f0 = __half22float2(ph[0]);
            const float2 f1 = __half22float2(ph[1]);
            const float2 f2 = __half22float2(ph[2]);
            const float2 f3 = __half22float2(ph[3]);
            a0 = fmaf(p, f0.x, a0); a1 = fmaf(p, f0.y, a1);
            a2 = fmaf(p, f1.x, a2); a3 = fmaf(p, f1.y, a3);
            a4 = fmaf(p, f2.x, a4); a5 = fmaf(p, f2.y, a5);
            a6 = fmaf(p, f3.x, a6); a7 = fmaf(p, f3.y, a7);
        }
    };

    // prologue: srcs for blocks 0..2; gathers for blocks 0,1 in flight
    LSRC(0, sv0); LSRC(1, sv1); LSRC(2, sv2);
    LHE(sv0, e0, g0);
    LHE(sv1, e1, g1);

    for (int t = 0; t < trips; ) {
        LHE(sv2, e2, g2); LSRC(t + 3, sv0); COMP(t, e0, g0); if (++t == trips) break;
        LHE(sv0, e0, g0); LSRC(t + 3, sv1); COMP(t, e1, g1); if (++t == trips) break;
        LHE(sv1, e1, g1); LSRC(t + 3, sv2); COMP(t, e2, g2); if (++t == trips) break;
    }

    if (!act) return;
    const float inv = 1.f / s;                // s > 0 (self loop)
    float o0 = a0 * inv, o1 = a1 * inv, o2 = a2 * inv, o3 = a3 * inv;
    float o4 = a4 * inv, o5 = a5 * inv, o6 = a6 * inv, o7 = a7 * inv;

    if (mode == 0) {
        const float4 b0 = ((const float4*)bias)[nl * 2];
        const float4 b1 = ((const float4*)bias)[nl * 2 + 1];
        o0 += b0.x; o1 += b0.y; o2 += b0.z; o3 += b0.w;
        o4 += b1.x; o5 += b1.y; o6 += b1.z; o7 += b1.w;
        o0 = (o0 > 0.f) ? o0 : (__expf(o0) - 1.f);
        o1 = (o1 > 0.f) ? o1 : (__expf(o1) - 1.f);
        o2 = (o2 > 0.f) ? o2 : (__expf(o2) - 1.f);
        o3 = (o3 > 0.f) ? o3 : (__expf(o3) - 1.f);
        o4 = (o4 > 0.f) ? o4 : (__expf(o4) - 1.f);
        o5 = (o5 > 0.f) ? o5 : (__expf(o5) - 1.f);
        o6 = (o6 > 0.f) ? o6 : (__expf(o6) - 1.f);
        o7 = (o7 > 0.f) ? o7 : (__expf(o7) - 1.f);
        float4* dst = (float4*)(out + (size_t)n * 128 + nl * 8);
        dst[0] = make_float4(o0, o1, o2, o3);
        dst[1] = make_float4(o4, o5, o6, o7);
    } else {
        const float q0 = __shfl_xor(o0, 8, 64);   // head partner within group
        const float q1 = __shfl_xor(o1, 8, 64);
        const float q2 = __shfl_xor(o2, 8, 64);
        const float q3 = __shfl_xor(o3, 8, 64);
        const float q4 = __shfl_xor(o4, 8, 64);
        const float q5 = __shfl_xor(o5, 8, 64);
        const float q6 = __shfl_xor(o6, 8, 64);
        const float q7 = __shfl_xor(o7, 8, 64);
        if (nl < 8) {
            const float4 b0 = ((const float4*)bias)[nl * 2];
            const float4 b1 = ((const float4*)bias)[nl * 2 + 1];
            float4* dst = (float4*)(out + (size_t)n * 64 + nl * 8);
            dst[0] = make_float4(0.5f * (o0 + q0) + b0.x, 0.5f * (o1 + q1) + b0.y,
                                 0.5f * (o2 + q2) + b0.z, 0.5f * (o3 + q3) + b0.w);
            dst[1] = make_float4(0.5f * (o4 + q4) + b1.x, 0.5f * (o5 + q5) + b1.y,
                                 0.5f * (o6 + q6) + b1.z, 0.5f * (o7 + q7) + b1.w);
        }
    }
}

// ---------------------------------------------------------------------------
extern "C" void kernel_launch(void* const* d_in, const int* in_sizes, int n_in,
                              void* d_out, int out_size, void* d_ws, size_t ws_size,
                              hipStream_t stream)
{
    const float* x   = (const float*)d_in[0];
    const int*   eix = (const int*)d_in[1];   // [2, E] int32
    const float* W1  = (const float*)d_in[2];
    const float* as1 = (const float*)d_in[3];
    const float* ad1 = (const float*)d_in[4];
    const float* b1  = (const float*)d_in[5];
    const float* W2  = (const float*)d_in[6];
    const float* as2 = (const float*)d_in[7];
    const float* ad2 = (const float*)d_in[8];
    const float* b2  = (const float*)d_in[9];
    float* out = (float*)d_out;

    const int N = in_sizes[0] / 128;
    const int E = in_sizes[1] / 2;
    const int Etot = E + N;
    const int* esrc = eix;
    const int* edst = eix + E;

    // ---- workspace layout (~87 MB) ----
    char* p = (char*)d_ws;
    __half*   h16    = (__half*)p;   p += (size_t)N * 128 * 2;
    float*    y1     = (float*)p;    p += (size_t)N * 128 * 4;
    float*    al     = (float*)p;    p += (size_t)N * 4 * 4;
    int*      cnt    = (int*)p;      p += (size_t)N * 4;
    unsigned* ub     = (unsigned*)p; p += 64;                 // [0..1] L1, [2..3] L2
    int*      incl   = (int*)p;      p += (size_t)N * 4;
    int*      dstptr = (int*)p;      p += (size_t)(N + 1) * 4;
    int*      cursor = (int*)p;      p += (size_t)N * 4;
    int*      bs1    = (int*)p;      p += 1024 * 4;
    int*      ssrc   = (int*)p;      p += (size_t)(Etot + 256) * 4;  // pipeline pad

    hipMemsetAsync(cnt, 0, (size_t)N * 4 + 64, stream);      // cnt + ub
    hipMemsetAsync(ssrc + Etot, 0, 256 * 4, stream);         // zero tail pad

    // ---- CSR by destination (shared by both layers) ----
    {
        const int eblocks = (Etot + 255) / 256;
        const int B0 = (N + 1023) / 1024;
        count_kernel<<<eblocks, 256, 0, stream>>>(edst, cnt, E, N);
        scan_local_kernel<<<B0, 1024, 0, stream>>>(cnt, incl, bs1, N);
        scan_excl_single_kernel<<<1, 1024, 0, stream>>>(bs1, B0);
        finalize_csr_kernel<<<(N + 1024) / 1024, 1024, 0, stream>>>(
            incl, cnt, bs1, dstptr, cursor, N, Etot);
        const int sliceN = (N + 7) / 8;
        const int bps = 512;
        scatter_kernel<<<bps * 8, 256, 0, stream>>>(esrc, edst, cursor, ssrc,
                                                    E, N, sliceN, bps);
    }

    const int ggrid = (N + 63) / 64;                   // 64 rows/block (MFMA)
    const int ablocks = (N + 15) / 16;                 // 16 nodes per 256-thr block

    // ---- Layer 1 ----
    gemm_al_kernel<<<ggrid, 256, 0, stream>>>(x, W1, as1, ad1, h16, al, ub, N);
    aggregate_kernel<<<ablocks, 256, 0, stream>>>(h16, al, dstptr, ssrc, ub, b1, y1, N, 0);

    // ---- Layer 2 ----
    gemm_al_kernel<<<ggrid, 256, 0, stream>>>(y1, W2, as2, ad2, h16, al, ub + 2, N);
    aggregate_kernel<<<ablocks, 256, 0, stream>>>(h16, al, dstptr, ssrc, ub + 2, b2, out, N, 1);
}

// Round 10
// 401.188 us; speedup vs baseline: 1.0440x; 1.0440x over previous
//
#include <hip/hip_runtime.h>
#include <hip/hip_fp16.h>

#define NEG_SLOPE 0.2f
#define LOG2E 1.4426950408889634f

typedef _Float16 half4v __attribute__((ext_vector_type(4)));
typedef _Float16 half8v __attribute__((ext_vector_type(8)));
typedef float f32x4 __attribute__((ext_vector_type(4)));

// ---------------------------------------------------------------------------
// float<->ordered-uint encoding for atomicMax on floats
// ---------------------------------------------------------------------------
__device__ inline unsigned enc_max(float f) {
    unsigned b = __float_as_uint(f);
    return (b & 0x80000000u) ? ~b : (b | 0x80000000u);
}
__device__ inline float dec_max(unsigned k) {
    return (k & 0x80000000u) ? __uint_as_float(k ^ 0x80000000u)
                             : __uint_as_float(~k);
}

// ---------------------------------------------------------------------------
// MFMA GEMM + attention projections (unchanged from R9).
//   H16[r,:] = fp16(X[r,:] @ W); AL[r] = (als_h0, als_h1, ald_h0, ald_h1)
// AL PRE-SCALED by log2(e): aggregate uses exp2 (softmax invariant).
// ---------------------------------------------------------------------------
__global__ __launch_bounds__(256) void gemm_al_kernel(
    const float* __restrict__ X, const float* __restrict__ W,
    const float* __restrict__ asrc, const float* __restrict__ adst,
    __half* __restrict__ H16, float* __restrict__ AL,
    unsigned* __restrict__ ubp, int N)
{
    __shared__ alignas(16) char smem[49152];

    const int t = threadIdx.x, lane = t & 63, wave = t >> 6;
    const int r0 = blockIdx.x * 64;

    // ---- stage X (fp32 -> fp16, swizzled 16B slots) ----
#pragma unroll
    for (int i = 0; i < 8; i++) {
        const int f = t + i * 256;
        const int row = f >> 5, k4 = f & 31;
        const int k8 = k4 >> 1, hf = k4 & 1;
        float4 v = make_float4(0.f, 0.f, 0.f, 0.f);
        if (r0 + row < N) v = ((const float4*)X)[(size_t)(r0 + row) * 32 + k4];
        half4v h = { (_Float16)v.x, (_Float16)v.y, (_Float16)v.z, (_Float16)v.w };
        const int slot = row * 16 + (k8 ^ (row & 7));
        *(half4v*)(smem + slot * 16 + hf * 8) = h;
    }
    // ---- stage W^T (fp32 -> fp16, swizzled) ----
    {
        const int c = t >> 1, kh = t & 1;
        const float* Wc = W + c;
#pragma unroll
        for (int i8 = 0; i8 < 8; i8++) {
            const int k0 = kh * 64 + i8 * 8;
            half8v h;
#pragma unroll
            for (int j = 0; j < 8; j++) h[j] = (_Float16)Wc[(size_t)(k0 + j) * 128];
            const int slot = c * 16 + ((k0 >> 3) ^ (c & 7));
            *(half8v*)(smem + 16384 + slot * 16) = h;
        }
    }
    __syncthreads();

    // ---- MFMA ----
    const int mrow = wave * 16 + (lane & 15);
    const int kg = lane >> 4;
    half4v a[8];
#pragma unroll
    for (int ks = 0; ks < 8; ks++) {
        const int k0 = ks * 16 + kg * 4;
        const int slot = mrow * 16 + ((k0 >> 3) ^ (mrow & 7));
        a[ks] = *(const half4v*)(smem + slot * 16 + (k0 & 7) * 2);
    }
    f32x4 acc[8];
#pragma unroll
    for (int ct = 0; ct < 8; ct++) acc[ct] = (f32x4){0.f, 0.f, 0.f, 0.f};
#pragma unroll
    for (int ct = 0; ct < 8; ct++) {
        const int c = ct * 16 + (lane & 15);
        const char* sbase = smem + 16384 + c * 256;
        const int csw = c & 7;
#pragma unroll
        for (int ks = 0; ks < 8; ks++) {
            const int k0 = ks * 16 + kg * 4;
            const int slot = (k0 >> 3) ^ csw;
            half4v b = *(const half4v*)(sbase + slot * 16 + (k0 & 7) * 2);
            acc[ct] = __builtin_amdgcn_mfma_f32_16x16x16f16(a[ks], b, acc[ct], 0, 0, 0);
        }
    }

    // ---- AL projections (pre-scaled by log2e) + per-head max ----
    float psh0[4] = {0,0,0,0}, psh1[4] = {0,0,0,0};
    float pdh0[4] = {0,0,0,0}, pdh1[4] = {0,0,0,0};
#pragma unroll
    for (int ct = 0; ct < 8; ct++) {
        const int c = ct * 16 + (lane & 15);
        const float as = asrc[c] * LOG2E, ad = adst[c] * LOG2E;
#pragma unroll
        for (int r = 0; r < 4; r++) {
            if (ct < 4) { psh0[r] = fmaf(acc[ct][r], as, psh0[r]);
                          pdh0[r] = fmaf(acc[ct][r], ad, pdh0[r]); }
            else        { psh1[r] = fmaf(acc[ct][r], as, psh1[r]);
                          pdh1[r] = fmaf(acc[ct][r], ad, pdh1[r]); }
        }
    }
#pragma unroll
    for (int off = 1; off <= 8; off <<= 1) {
#pragma unroll
        for (int r = 0; r < 4; r++) {
            psh0[r] += __shfl_xor(psh0[r], off, 64);
            psh1[r] += __shfl_xor(psh1[r], off, 64);
            pdh0[r] += __shfl_xor(pdh0[r], off, 64);
            pdh1[r] += __shfl_xor(pdh1[r], off, 64);
        }
    }
    float rmax0 = -__builtin_inff(), rmax1 = -__builtin_inff();
    if ((lane & 15) == 0) {
#pragma unroll
        for (int r = 0; r < 4; r++) {
            const int gr = r0 + wave * 16 + (lane >> 4) * 4 + r;
            if (gr < N) {
                ((float4*)AL)[gr] = make_float4(psh0[r], psh1[r], pdh0[r], pdh1[r]);
                rmax0 = fmaxf(rmax0, psh0[r]);
                rmax1 = fmaxf(rmax1, psh1[r]);
            }
        }
    }
#pragma unroll
    for (int off = 32; off > 0; off >>= 1) {
        rmax0 = fmaxf(rmax0, __shfl_xor(rmax0, off, 64));
        rmax1 = fmaxf(rmax1, __shfl_xor(rmax1, off, 64));
    }

    // ---- D -> LDS (reuse staging), then coalesced fp16 write ----
    __syncthreads();
    float* Dst = (float*)smem;
    float* red = (float*)(smem + 33792);
    if (lane == 0) { red[wave * 2] = rmax0; red[wave * 2 + 1] = rmax1; }
#pragma unroll
    for (int ct = 0; ct < 8; ct++) {
        const int col = ct * 16 + (lane & 15);
        float* drow = Dst + wave * 2112 + ((lane >> 4) * 4) * 132 + col;
#pragma unroll
        for (int r = 0; r < 4; r++) drow[r * 132] = acc[ct][r];
    }
    __syncthreads();
    if (t < 2) {
        float m = fmaxf(fmaxf(red[t], red[2 + t]), fmaxf(red[4 + t], red[6 + t]));
        atomicMax(&ubp[t], enc_max(m));
    }
#pragma unroll
    for (int i = 0; i < 4; i++) {
        const int f = t + i * 256;
        const int row = f >> 4, c16 = f & 15;
        if (r0 + row < N) {
            const float* src = Dst + (row >> 4) * 2112 + (row & 15) * 132 + c16 * 8;
            const float4 v0 = *(const float4*)src;
            const float4 v1 = *(const float4*)(src + 4);
            half8v h = { (_Float16)v0.x, (_Float16)v0.y, (_Float16)v0.z, (_Float16)v0.w,
                         (_Float16)v1.x, (_Float16)v1.y, (_Float16)v1.z, (_Float16)v1.w };
            *(half8v*)((_Float16*)H16 + (size_t)(r0 + row) * 128 + c16 * 8) = h;
        }
    }
}

// ---------------------------------------------------------------------------
// CSR build + degree histogram (for degree-paired node ordering).
// ---------------------------------------------------------------------------
__global__ void count_kernel(const int* __restrict__ edst, int* __restrict__ cnt,
                             int E, int N)
{
    int i = blockIdx.x * 256 + threadIdx.x;
    if (i < E)            atomicAdd(&cnt[edst[i]], 1);
    else if (i < E + N)   atomicAdd(&cnt[i - E], 1);   // self loop
}

// scan of cnt (1024/block) + LDS-aggregated global degree histogram
__global__ void scan_local_kernel(const int* __restrict__ in, int* __restrict__ out,
                                  int* __restrict__ bsum, int* __restrict__ hist, int n)
{
    __shared__ int sm[1024];
    __shared__ int lh[256];
    const int t = threadIdx.x;
    const int i = blockIdx.x * 1024 + t;
    if (t < 256) lh[t] = 0;
    int v = (i < n) ? in[i] : 0;
    sm[t] = v;
    __syncthreads();
    if (i < n) atomicAdd(&lh[min(v, 255)], 1);
    for (int off = 1; off < 1024; off <<= 1) {
        int x = (t >= off) ? sm[t - off] : 0;
        __syncthreads();
        sm[t] += x;
        __syncthreads();
    }
    if (i < n) out[i] = sm[t];
    if (t == 1023) bsum[blockIdx.x] = sm[t];
    if (t < 256 && lh[t]) atomicAdd(&hist[t], lh[t]);
}

// exclusive scan of bsum[B] and hist[256], single block
__global__ void scan_excl_single_kernel(int* __restrict__ a, int B,
                                        int* __restrict__ hist)
{
    __shared__ int sm[1024];
    const int t = threadIdx.x;
    int v = (t < B) ? a[t] : 0;
    sm[t] = v;
    __syncthreads();
    for (int off = 1; off < 1024; off <<= 1) {
        int x = (t >= off) ? sm[t - off] : 0;
        __syncthreads();
        sm[t] += x;
        __syncthreads();
    }
    if (t < B) a[t] = sm[t] - v;   // exclusive
    __syncthreads();
    int h = (t < 256) ? hist[t] : 0;
    sm[t] = h;
    __syncthreads();
    for (int off = 1; off < 256; off <<= 1) {
        int x = (t >= off && t < 256) ? sm[t - off] : 0;
        __syncthreads();
        if (t < 256) sm[t] += x;
        __syncthreads();
    }
    if (t < 256) hist[t] = sm[t] - h;   // exclusive bases
}

// finalize CSR + scatter node ids into degree-sorted order[]
__global__ void finalize_csr_kernel(const int* __restrict__ incl,
                                    const int* __restrict__ cnt,
                                    const int* __restrict__ bexcl,
                                    int* __restrict__ dstptr, int* __restrict__ cursor,
                                    int* __restrict__ hist, int* __restrict__ order,
                                    int N, int Etot)
{
    __shared__ int lh[256], lbase[256];
    const int t = threadIdx.x;
    const int i = blockIdx.x * 1024 + t;
    if (t < 256) lh[t] = 0;
    __syncthreads();
    int bin = 0;
    if (i < N) {
        const int c = cnt[i];
        const int v = incl[i] + bexcl[i >> 10] - c;
        dstptr[i] = v;
        cursor[i] = v;
        bin = min(c, 255);
        atomicAdd(&lh[bin], 1);
    }
    if (i == N) dstptr[N] = Etot;
    __syncthreads();
    if (t < 256) { lbase[t] = lh[t] ? atomicAdd(&hist[t], lh[t]) : 0; lh[t] = 0; }
    __syncthreads();
    if (i < N) {
        const int off = atomicAdd(&lh[bin], 1);
        order[lbase[bin] + off] = i;
    }
}

// Sliced scatter: blocks with blockIdx%8==s handle dst slice s (-> one XCD by
// round-robin dispatch), so each ssrc cache line is written by one XCD only.
__global__ void scatter_kernel(const int* __restrict__ esrc, const int* __restrict__ edst,
                               int* __restrict__ cursor, int* __restrict__ ssrc,
                               int E, int N, int sliceN, int bps)
{
    const int slice = blockIdx.x & 7;
    const int dlo = slice * sliceN;
    const int dhi = min(N, dlo + sliceN);
    const int Etot = E + N;
    for (int i = (blockIdx.x >> 3) * 256 + (int)threadIdx.x; i < Etot; i += bps * 256) {
        int s, d;
        if (i < E) { s = esrc[i]; d = edst[i]; }
        else       { s = d = i - E; }
        if (d >= dlo && d < dhi) {
            int pos = atomicAdd(&cursor[d], 1);
            ssrc[pos] = s;
        }
    }
}

// ---------------------------------------------------------------------------
// Aggregation, shifted softmax in exp2 domain. TWO degree-paired nodes per
// wave (via order[]): lanes 0-31 node A, 32-63 node B; lane owns 4 channels
// (8B gathers); head = nl>>4. Mov-free 3-slot ring over 4-edge blocks;
// unified mask rem = edges - 4t.
// mode 0: out[n,128] = ELU(acc/s + b)   mode 1: out[n,64] = mean_h(acc/s)+b
// ---------------------------------------------------------------------------
__global__ __launch_bounds__(256) void aggregate_kernel(
    const __half* __restrict__ H16, const float* __restrict__ AL,
    const int* __restrict__ dstptr, const int* __restrict__ ssrc,
    const int* __restrict__ order, const unsigned* __restrict__ ubenc,
    const float* __restrict__ bias, float* __restrict__ out, int N, int mode)
{
    const int wid  = (blockIdx.x * blockDim.x + threadIdx.x) >> 6;
    const int lane = threadIdx.x & 63;
    if (wid * 2 >= N) return;
    const int nidx = wid * 2 + (lane >> 5);
    const bool act = (nidx < N);
    const int n    = order[act ? nidx : N - 1];
    const int beg  = dstptr[n];
    const int edges = act ? (dstptr[n + 1] - beg) : 0;
    const int nl   = lane & 31;
    const int head = nl >> 4;

    const float ald = AL[(size_t)n * 4 + 2 + head];
    float ub = dec_max(ubenc[head]) + ald;
    ub = fmaxf(ub, NEG_SLOPE * ub);           // leaky, scale-invariant

    int tr = (edges + 3) >> 2;
    tr = max(tr, __shfl_xor(tr, 32, 64));
    const int trips = tr;

    float s = 0.f, a0 = 0.f, a1 = 0.f, a2 = 0.f, a3 = 0.f;

    int   sv0[4], sv1[4], sv2[4];
    float e0[4], e1[4], e2[4];
    uint2 g0[4], g1[4], g2[4];

    auto LSRC = [&](int b, int (&sv)[4]) {
#pragma unroll
        for (int k = 0; k < 4; k++) sv[k] = ssrc[beg + 4 * b + k];  // padded: safe
    };
    auto LHE = [&](const int (&sv)[4], float (&e)[4], uint2 (&g)[4]) {
#pragma unroll
        for (int k = 0; k < 4; k++) {
            e[k] = AL[(size_t)sv[k] * 4 + head];
            g[k] = ((const uint2*)(H16 + (size_t)sv[k] * 128))[nl];
        }
    };
    auto COMP = [&](int t, const float (&e)[4], const uint2 (&g)[4]) {
        const int rem = edges - 4 * t;        // <=0 for overflow/inactive
#pragma unroll
        for (int k = 0; k < 4; k++) {
            float tt = e[k] + ald;
            tt = fmaxf(tt, NEG_SLOPE * tt);   // leaky (logits pre-scaled)
            float p = exp2f(tt - ub);
            p = (k < rem) ? p : 0.f;          // unified mask
            s += p;
            const __half2* ph = (const __half2*)&g[k];
            const float2 f01 = __half22float2(ph[0]);
            const float2 f23 = __half22float2(ph[1]);
            a0 = fmaf(p, f01.x, a0);
            a1 = fmaf(p, f01.y, a1);
            a2 = fmaf(p, f23.x, a2);
            a3 = fmaf(p, f23.y, a3);
        }
    };

    // prologue: srcs for blocks 0..2; gathers for blocks 0,1 in flight
    LSRC(0, sv0); LSRC(1, sv1); LSRC(2, sv2);
    LHE(sv0, e0, g0);
    LHE(sv1, e1, g1);

    for (int t = 0; t < trips; ) {
        LHE(sv2, e2, g2); LSRC(t + 3, sv0); COMP(t, e0, g0); if (++t == trips) break;
        LHE(sv0, e0, g0); LSRC(t + 3, sv1); COMP(t, e1, g1); if (++t == trips) break;
        LHE(sv1, e1, g1); LSRC(t + 3, sv2); COMP(t, e2, g2); if (++t == trips) break;
    }

    if (!act) return;
    const float inv = 1.f / s;                // s > 0 (self loop)
    float o0 = a0 * inv, o1 = a1 * inv, o2 = a2 * inv, o3 = a3 * inv;

    if (mode == 0) {
        const float4 b4 = ((const float4*)bias)[nl];
        o0 += b4.x; o1 += b4.y; o2 += b4.z; o3 += b4.w;
        o0 = (o0 > 0.f) ? o0 : (__expf(o0) - 1.f);
        o1 = (o1 > 0.f) ? o1 : (__expf(o1) - 1.f);
        o2 = (o2 > 0.f) ? o2 : (__expf(o2) - 1.f);
        o3 = (o3 > 0.f) ? o3 : (__expf(o3) - 1.f);
        ((float4*)out)[(size_t)n * 32 + nl] = make_float4(o0, o1, o2, o3);
    } else {
        const float q0 = __shfl_xor(o0, 16, 64);   // head partner within node
        const float q1 = __shfl_xor(o1, 16, 64);
        const float q2 = __shfl_xor(o2, 16, 64);
        const float q3 = __shfl_xor(o3, 16, 64);
        if (nl < 16) {
            const float4 b4 = ((const float4*)bias)[nl];
            ((float4*)out)[(size_t)n * 16 + nl] =
                make_float4(0.5f * (o0 + q0) + b4.x, 0.5f * (o1 + q1) + b4.y,
                            0.5f * (o2 + q2) + b4.z, 0.5f * (o3 + q3) + b4.w);
        }
    }
}

// ---------------------------------------------------------------------------
extern "C" void kernel_launch(void* const* d_in, const int* in_sizes, int n_in,
                              void* d_out, int out_size, void* d_ws, size_t ws_size,
                              hipStream_t stream)
{
    const float* x   = (const float*)d_in[0];
    const int*   eix = (const int*)d_in[1];   // [2, E] int32
    const float* W1  = (const float*)d_in[2];
    const float* as1 = (const float*)d_in[3];
    const float* ad1 = (const float*)d_in[4];
    const float* b1  = (const float*)d_in[5];
    const float* W2  = (const float*)d_in[6];
    const float* as2 = (const float*)d_in[7];
    const float* ad2 = (const float*)d_in[8];
    const float* b2  = (const float*)d_in[9];
    float* out = (float*)d_out;

    const int N = in_sizes[0] / 128;
    const int E = in_sizes[1] / 2;
    const int Etot = E + N;
    const int* esrc = eix;
    const int* edst = eix + E;

    // ---- workspace layout (~88 MB) ----
    char* p = (char*)d_ws;
    __half*   h16    = (__half*)p;   p += (size_t)N * 128 * 2;
    float*    y1     = (float*)p;    p += (size_t)N * 128 * 4;
    float*    al     = (float*)p;    p += (size_t)N * 4 * 4;
    int*      cnt    = (int*)p;      p += (size_t)N * 4;
    unsigned* ub     = (unsigned*)p; p += 64;                 // [0..1] L1, [2..3] L2
    int*      hist   = (int*)p;      p += 256 * 4;
    int*      incl   = (int*)p;      p += (size_t)N * 4;
    int*      dstptr = (int*)p;      p += (size_t)(N + 1) * 4;
    int*      cursor = (int*)p;      p += (size_t)N * 4;
    int*      order  = (int*)p;      p += (size_t)N * 4;
    int*      bs1    = (int*)p;      p += 1024 * 4;
    int*      ssrc   = (int*)p;      p += (size_t)(Etot + 256) * 4;  // pipeline pad

    hipMemsetAsync(cnt, 0, (size_t)N * 4 + 64 + 1024, stream);  // cnt + ub + hist
    hipMemsetAsync(ssrc + Etot, 0, 256 * 4, stream);            // zero tail pad

    // ---- CSR by destination + degree-sorted order (shared by both layers) ----
    {
        const int eblocks = (Etot + 255) / 256;
        const int B0 = (N + 1023) / 1024;
        count_kernel<<<eblocks, 256, 0, stream>>>(edst, cnt, E, N);
        scan_local_kernel<<<B0, 1024, 0, stream>>>(cnt, incl, bs1, hist, N);
        scan_excl_single_kernel<<<1, 1024, 0, stream>>>(bs1, B0, hist);
        finalize_csr_kernel<<<(N + 1024) / 1024, 1024, 0, stream>>>(
            incl, cnt, bs1, dstptr, cursor, hist, order, N, Etot);
        const int sliceN = (N + 7) / 8;
        const int bps = 512;
        scatter_kernel<<<bps * 8, 256, 0, stream>>>(esrc, edst, cursor, ssrc,
                                                    E, N, sliceN, bps);
    }

    const int ggrid = (N + 63) / 64;                   // 64 rows/block (MFMA)
    const int ablocks = (N + 7) / 8;                   // 8 nodes per 256-thr block

    // ---- Layer 1 ----
    gemm_al_kernel<<<ggrid, 256, 0, stream>>>(x, W1, as1, ad1, h16, al, ub, N);
    aggregate_kernel<<<ablocks, 256, 0, stream>>>(h16, al, dstptr, ssrc, order,
                                                  ub, b1, y1, N, 0);

    // ---- Layer 2 ----
    gemm_al_kernel<<<ggrid, 256, 0, stream>>>(y1, W2, as2, ad2, h16, al, ub + 2, N);
    aggregate_kernel<<<ablocks, 256, 0, stream>>>(h16, al, dstptr, ssrc, order,
                                                  ub + 2, b2, out, N, 1);
}

// Round 11
// 385.485 us; speedup vs baseline: 1.0865x; 1.0407x over previous
//
#include <hip/hip_runtime.h>
#include <hip/hip_fp16.h>

#define NEG_SLOPE 0.2f
#define LOG2E 1.4426950408889634f

typedef _Float16 half4v __attribute__((ext_vector_type(4)));
typedef _Float16 half8v __attribute__((ext_vector_type(8)));
typedef float f32x4 __attribute__((ext_vector_type(4)));

// ---------------------------------------------------------------------------
// float<->ordered-uint encoding for atomicMax on floats
// ---------------------------------------------------------------------------
__device__ inline unsigned enc_max(float f) {
    unsigned b = __float_as_uint(f);
    return (b & 0x80000000u) ? ~b : (b | 0x80000000u);
}
__device__ inline float dec_max(unsigned k) {
    return (k & 0x80000000u) ? __uint_as_float(k ^ 0x80000000u)
                             : __uint_as_float(~k);
}

// ---------------------------------------------------------------------------
// MFMA GEMM + attention projections.
//   H16[r,:] = fp16(X[r,:] @ W); AL[r] = (als_h0, als_h1, ald_h0, ald_h1)
// AL PRE-SCALED by log2(e): aggregate uses exp2 (softmax invariant).
// ---------------------------------------------------------------------------
__global__ __launch_bounds__(256) void gemm_al_kernel(
    const float* __restrict__ X, const float* __restrict__ W,
    const float* __restrict__ asrc, const float* __restrict__ adst,
    __half* __restrict__ H16, float* __restrict__ AL,
    unsigned* __restrict__ ubp, int N)
{
    __shared__ alignas(16) char smem[49152];

    const int t = threadIdx.x, lane = t & 63, wave = t >> 6;
    const int r0 = blockIdx.x * 64;

    // ---- stage X (fp32 -> fp16, swizzled 16B slots) ----
#pragma unroll
    for (int i = 0; i < 8; i++) {
        const int f = t + i * 256;
        const int row = f >> 5, k4 = f & 31;
        const int k8 = k4 >> 1, hf = k4 & 1;
        float4 v = make_float4(0.f, 0.f, 0.f, 0.f);
        if (r0 + row < N) v = ((const float4*)X)[(size_t)(r0 + row) * 32 + k4];
        half4v h = { (_Float16)v.x, (_Float16)v.y, (_Float16)v.z, (_Float16)v.w };
        const int slot = row * 16 + (k8 ^ (row & 7));
        *(half4v*)(smem + slot * 16 + hf * 8) = h;
    }
    // ---- stage W^T (fp32 -> fp16, swizzled) ----
    {
        const int c = t >> 1, kh = t & 1;
        const float* Wc = W + c;
#pragma unroll
        for (int i8 = 0; i8 < 8; i8++) {
            const int k0 = kh * 64 + i8 * 8;
            half8v h;
#pragma unroll
            for (int j = 0; j < 8; j++) h[j] = (_Float16)Wc[(size_t)(k0 + j) * 128];
            const int slot = c * 16 + ((k0 >> 3) ^ (c & 7));
            *(half8v*)(smem + 16384 + slot * 16) = h;
        }
    }
    __syncthreads();

    // ---- MFMA ----
    const int mrow = wave * 16 + (lane & 15);
    const int kg = lane >> 4;
    half4v a[8];
#pragma unroll
    for (int ks = 0; ks < 8; ks++) {
        const int k0 = ks * 16 + kg * 4;
        const int slot = mrow * 16 + ((k0 >> 3) ^ (mrow & 7));
        a[ks] = *(const half4v*)(smem + slot * 16 + (k0 & 7) * 2);
    }
    f32x4 acc[8];
#pragma unroll
    for (int ct = 0; ct < 8; ct++) acc[ct] = (f32x4){0.f, 0.f, 0.f, 0.f};
#pragma unroll
    for (int ct = 0; ct < 8; ct++) {
        const int c = ct * 16 + (lane & 15);
        const char* sbase = smem + 16384 + c * 256;
        const int csw = c & 7;
#pragma unroll
        for (int ks = 0; ks < 8; ks++) {
            const int k0 = ks * 16 + kg * 4;
            const int slot = (k0 >> 3) ^ csw;
            half4v b = *(const half4v*)(sbase + slot * 16 + (k0 & 7) * 2);
            acc[ct] = __builtin_amdgcn_mfma_f32_16x16x16f16(a[ks], b, acc[ct], 0, 0, 0);
        }
    }

    // ---- AL projections (pre-scaled by log2e) + per-head max ----
    float psh0[4] = {0,0,0,0}, psh1[4] = {0,0,0,0};
    float pdh0[4] = {0,0,0,0}, pdh1[4] = {0,0,0,0};
#pragma unroll
    for (int ct = 0; ct < 8; ct++) {
        const int c = ct * 16 + (lane & 15);
        const float as = asrc[c] * LOG2E, ad = adst[c] * LOG2E;
#pragma unroll
        for (int r = 0; r < 4; r++) {
            if (ct < 4) { psh0[r] = fmaf(acc[ct][r], as, psh0[r]);
                          pdh0[r] = fmaf(acc[ct][r], ad, pdh0[r]); }
            else        { psh1[r] = fmaf(acc[ct][r], as, psh1[r]);
                          pdh1[r] = fmaf(acc[ct][r], ad, pdh1[r]); }
        }
    }
#pragma unroll
    for (int off = 1; off <= 8; off <<= 1) {
#pragma unroll
        for (int r = 0; r < 4; r++) {
            psh0[r] += __shfl_xor(psh0[r], off, 64);
            psh1[r] += __shfl_xor(psh1[r], off, 64);
            pdh0[r] += __shfl_xor(pdh0[r], off, 64);
            pdh1[r] += __shfl_xor(pdh1[r], off, 64);
        }
    }
    float rmax0 = -__builtin_inff(), rmax1 = -__builtin_inff();
    if ((lane & 15) == 0) {
#pragma unroll
        for (int r = 0; r < 4; r++) {
            const int gr = r0 + wave * 16 + (lane >> 4) * 4 + r;
            if (gr < N) {
                ((float4*)AL)[gr] = make_float4(psh0[r], psh1[r], pdh0[r], pdh1[r]);
                rmax0 = fmaxf(rmax0, psh0[r]);
                rmax1 = fmaxf(rmax1, psh1[r]);
            }
        }
    }
#pragma unroll
    for (int off = 32; off > 0; off >>= 1) {
        rmax0 = fmaxf(rmax0, __shfl_xor(rmax0, off, 64));
        rmax1 = fmaxf(rmax1, __shfl_xor(rmax1, off, 64));
    }

    // ---- D -> LDS (reuse staging), then coalesced fp16 write ----
    __syncthreads();
    float* Dst = (float*)smem;
    float* red = (float*)(smem + 33792);
    if (lane == 0) { red[wave * 2] = rmax0; red[wave * 2 + 1] = rmax1; }
#pragma unroll
    for (int ct = 0; ct < 8; ct++) {
        const int col = ct * 16 + (lane & 15);
        float* drow = Dst + wave * 2112 + ((lane >> 4) * 4) * 132 + col;
#pragma unroll
        for (int r = 0; r < 4; r++) drow[r * 132] = acc[ct][r];
    }
    __syncthreads();
    if (t < 2) {
        float m = fmaxf(fmaxf(red[t], red[2 + t]), fmaxf(red[4 + t], red[6 + t]));
        atomicMax(&ubp[t], enc_max(m));
    }
#pragma unroll
    for (int i = 0; i < 4; i++) {
        const int f = t + i * 256;
        const int row = f >> 4, c16 = f & 15;
        if (r0 + row < N) {
            const float* src = Dst + (row >> 4) * 2112 + (row & 15) * 132 + c16 * 8;
            const float4 v0 = *(const float4*)src;
            const float4 v1 = *(const float4*)(src + 4);
            half8v h = { (_Float16)v0.x, (_Float16)v0.y, (_Float16)v0.z, (_Float16)v0.w,
                         (_Float16)v1.x, (_Float16)v1.y, (_Float16)v1.z, (_Float16)v1.w };
            *(half8v*)((_Float16*)H16 + (size_t)(r0 + row) * 128 + c16 * 8) = h;
        }
    }
}

// ---------------------------------------------------------------------------
// CSR build: sliced count -> scan -> finalize -> sliced scatter.
// Slicing by dst keeps each cnt/cursor/ssrc line owned by one XCD.
// ---------------------------------------------------------------------------
__global__ void count_kernel(const int* __restrict__ edst, int* __restrict__ cnt,
                             int E, int N, int sliceN, int bps)
{
    const int slice = blockIdx.x & 7;
    const int dlo = slice * sliceN;
    const int dhi = min(N, dlo + sliceN);
    const int Etot = E + N;
    for (int i = (blockIdx.x >> 3) * 256 + (int)threadIdx.x; i < Etot; i += bps * 256) {
        const int d = (i < E) ? edst[i] : (i - E);
        if (d >= dlo && d < dhi) atomicAdd(&cnt[d], 1);
    }
}

__global__ void scan_local_kernel(const int* __restrict__ in, int* __restrict__ out,
                                  int* __restrict__ bsum, int n)
{
    __shared__ int sm[1024];
    const int t = threadIdx.x;
    const int i = blockIdx.x * 1024 + t;
    int v = (i < n) ? in[i] : 0;
    sm[t] = v;
    __syncthreads();
    for (int off = 1; off < 1024; off <<= 1) {
        int x = (t >= off) ? sm[t - off] : 0;
        __syncthreads();
        sm[t] += x;
        __syncthreads();
    }
    if (i < n) out[i] = sm[t];
    if (t == 1023) bsum[blockIdx.x] = sm[t];
}

__global__ void scan_excl_single_kernel(int* __restrict__ a, int B)
{
    __shared__ int sm[1024];
    const int t = threadIdx.x;
    int v = (t < B) ? a[t] : 0;
    sm[t] = v;
    __syncthreads();
    for (int off = 1; off < 1024; off <<= 1) {
        int x = (t >= off) ? sm[t - off] : 0;
        __syncthreads();
        sm[t] += x;
        __syncthreads();
    }
    if (t < B) a[t] = sm[t] - v;   // exclusive
}

__global__ void finalize_csr_kernel(const int* __restrict__ incl,
                                    const int* __restrict__ cnt,
                                    const int* __restrict__ bexcl,
                                    int* __restrict__ dstptr, int* __restrict__ cursor,
                                    int N, int Etot)
{
    const int i = blockIdx.x * 1024 + threadIdx.x;
    if (i < N) {
        int v = incl[i] + bexcl[i >> 10] - cnt[i];
        dstptr[i] = v;
        cursor[i] = v;
    }
    if (i == N) dstptr[N] = Etot;
}

__global__ void scatter_kernel(const int* __restrict__ esrc, const int* __restrict__ edst,
                               int* __restrict__ cursor, int* __restrict__ ssrc,
                               int E, int N, int sliceN, int bps)
{
    const int slice = blockIdx.x & 7;
    const int dlo = slice * sliceN;
    const int dhi = min(N, dlo + sliceN);
    const int Etot = E + N;
    for (int i = (blockIdx.x >> 3) * 256 + (int)threadIdx.x; i < Etot; i += bps * 256) {
        int s, d;
        if (i < E) { s = esrc[i]; d = edst[i]; }
        else       { s = d = i - E; }
        if (d >= dlo && d < dhi) {
            int pos = atomicAdd(&cursor[d], 1);
            ssrc[pos] = s;
        }
    }
}

// ---------------------------------------------------------------------------
// Aggregation, shifted softmax in exp2 domain. TWO nodes per wave (lanes
// 0-31 node A, 32-63 node B); lane owns 4 channels (uint2 = 8B gathers);
// head = nl>>4. Mov-free 3-slot ring over 4-edge blocks.
// Masked slots clamp src to row 0 (always L2-hot) and zero p via rem mask.
// mode 0: out[n,128] = ELU(acc/s + b)   mode 1: out[n,64] = mean_h(acc/s)+b
// ---------------------------------------------------------------------------
__global__ __launch_bounds__(256) void aggregate_kernel(
    const __half* __restrict__ H16, const float* __restrict__ AL,
    const int* __restrict__ dstptr, const int* __restrict__ ssrc,
    const unsigned* __restrict__ ubenc, const float* __restrict__ bias,
    float* __restrict__ out, int N, int mode)
{
    const int wid  = (blockIdx.x * blockDim.x + threadIdx.x) >> 6;
    const int lane = threadIdx.x & 63;
    if (wid * 2 >= N) return;
    const int n    = wid * 2 + (lane >> 5);
    const bool act = (n < N);
    const int nn   = act ? n : (N - 1);
    const int beg  = dstptr[nn];
    const int edges = act ? (dstptr[nn + 1] - beg) : 0;
    const int nl   = lane & 31;
    const int head = nl >> 4;

    const float ald = AL[(size_t)nn * 4 + 2 + head];
    float ub = dec_max(ubenc[head]) + ald;
    ub = fmaxf(ub, NEG_SLOPE * ub);           // leaky, scale-invariant

    int tr = (edges + 3) >> 2;
    tr = max(tr, __shfl_xor(tr, 32, 64));
    const int trips = tr;

    float s = 0.f, a0 = 0.f, a1 = 0.f, a2 = 0.f, a3 = 0.f;

    int   sv0[4], sv1[4], sv2[4];
    float e0[4], e1[4], e2[4];
    uint2 g0[4], g1[4], g2[4];

    auto LSRC = [&](int b, int (&sv)[4]) {
#pragma unroll
        for (int k = 0; k < 4; k++) {
            const int idx = 4 * b + k;
            const int v = ssrc[beg + idx];    // padded: safe
            sv[k] = (idx < edges) ? v : 0;    // clamp masked -> hot row 0
        }
    };
    auto LHE = [&](const int (&sv)[4], float (&e)[4], uint2 (&g)[4]) {
#pragma unroll
        for (int k = 0; k < 4; k++) {
            e[k] = AL[(size_t)sv[k] * 4 + head];
            g[k] = ((const uint2*)(H16 + (size_t)sv[k] * 128))[nl];
        }
    };
    auto COMP = [&](int t, const float (&e)[4], const uint2 (&g)[4]) {
        const int rem = edges - 4 * t;        // <=0 for overflow/inactive
#pragma unroll
        for (int k = 0; k < 4; k++) {
            float tt = e[k] + ald;
            tt = fmaxf(tt, NEG_SLOPE * tt);   // leaky (logits pre-scaled)
            float p = exp2f(tt - ub);
            p = (k < rem) ? p : 0.f;          // mask
            s += p;
            const __half2* ph = (const __half2*)&g[k];
            const float2 f01 = __half22float2(ph[0]);
            const float2 f23 = __half22float2(ph[1]);
            a0 = fmaf(p, f01.x, a0);
            a1 = fmaf(p, f01.y, a1);
            a2 = fmaf(p, f23.x, a2);
            a3 = fmaf(p, f23.y, a3);
        }
    };

    // prologue: srcs for blocks 0..2; gathers for blocks 0,1 in flight
    LSRC(0, sv0); LSRC(1, sv1); LSRC(2, sv2);
    LHE(sv0, e0, g0);
    LHE(sv1, e1, g1);

    for (int t = 0; t < trips; ) {
        LHE(sv2, e2, g2); LSRC(t + 3, sv0); COMP(t, e0, g0); if (++t == trips) break;
        LHE(sv0, e0, g0); LSRC(t + 3, sv1); COMP(t, e1, g1); if (++t == trips) break;
        LHE(sv1, e1, g1); LSRC(t + 3, sv2); COMP(t, e2, g2); if (++t == trips) break;
    }

    if (!act) return;
    const float inv = 1.f / s;                // s > 0 (self loop)
    float o0 = a0 * inv, o1 = a1 * inv, o2 = a2 * inv, o3 = a3 * inv;

    if (mode == 0) {
        const float4 b4 = ((const float4*)bias)[nl];
        o0 += b4.x; o1 += b4.y; o2 += b4.z; o3 += b4.w;
        o0 = (o0 > 0.f) ? o0 : (__expf(o0) - 1.f);
        o1 = (o1 > 0.f) ? o1 : (__expf(o1) - 1.f);
        o2 = (o2 > 0.f) ? o2 : (__expf(o2) - 1.f);
        o3 = (o3 > 0.f) ? o3 : (__expf(o3) - 1.f);
        ((float4*)out)[(size_t)n * 32 + nl] = make_float4(o0, o1, o2, o3);
    } else {
        const float q0 = __shfl_xor(o0, 16, 64);   // head partner within node
        const float q1 = __shfl_xor(o1, 16, 64);
        const float q2 = __shfl_xor(o2, 16, 64);
        const float q3 = __shfl_xor(o3, 16, 64);
        if (nl < 16) {
            const float4 b4 = ((const float4*)bias)[nl];
            ((float4*)out)[(size_t)n * 16 + nl] =
                make_float4(0.5f * (o0 + q0) + b4.x, 0.5f * (o1 + q1) + b4.y,
                            0.5f * (o2 + q2) + b4.z, 0.5f * (o3 + q3) + b4.w);
        }
    }
}

// ---------------------------------------------------------------------------
extern "C" void kernel_launch(void* const* d_in, const int* in_sizes, int n_in,
                              void* d_out, int out_size, void* d_ws, size_t ws_size,
                              hipStream_t stream)
{
    const float* x   = (const float*)d_in[0];
    const int*   eix = (const int*)d_in[1];   // [2, E] int32
    const float* W1  = (const float*)d_in[2];
    const float* as1 = (const float*)d_in[3];
    const float* ad1 = (const float*)d_in[4];
    const float* b1  = (const float*)d_in[5];
    const float* W2  = (const float*)d_in[6];
    const float* as2 = (const float*)d_in[7];
    const float* ad2 = (const float*)d_in[8];
    const float* b2  = (const float*)d_in[9];
    float* out = (float*)d_out;

    const int N = in_sizes[0] / 128;
    const int E = in_sizes[1] / 2;
    const int Etot = E + N;
    const int* esrc = eix;
    const int* edst = eix + E;

    // ---- workspace layout (~87 MB) ----
    char* p = (char*)d_ws;
    __half*   h16    = (__half*)p;   p += (size_t)N * 128 * 2;
    float*    y1     = (float*)p;    p += (size_t)N * 128 * 4;
    float*    al     = (float*)p;    p += (size_t)N * 4 * 4;
    int*      cnt    = (int*)p;      p += (size_t)N * 4;
    unsigned* ub     = (unsigned*)p; p += 64;                 // [0..1] L1, [2..3] L2
    int*      incl   = (int*)p;      p += (size_t)N * 4;
    int*      dstptr = (int*)p;      p += (size_t)(N + 1) * 4;
    int*      cursor = (int*)p;      p += (size_t)N * 4;
    int*      bs1    = (int*)p;      p += 1024 * 4;
    int*      ssrc   = (int*)p;      p += (size_t)(Etot + 256) * 4;  // pipeline pad

    hipMemsetAsync(cnt, 0, (size_t)N * 4 + 64, stream);      // cnt + ub
    hipMemsetAsync(ssrc + Etot, 0, 256 * 4, stream);         // zero tail pad

    // ---- CSR by destination (shared by both layers) ----
    {
        const int B0 = (N + 1023) / 1024;
        const int sliceN = (N + 7) / 8;
        const int bps = 512;
        count_kernel<<<bps * 8, 256, 0, stream>>>(edst, cnt, E, N, sliceN, bps);
        scan_local_kernel<<<B0, 1024, 0, stream>>>(cnt, incl, bs1, N);
        scan_excl_single_kernel<<<1, 1024, 0, stream>>>(bs1, B0);
        finalize_csr_kernel<<<(N + 1024) / 1024, 1024, 0, stream>>>(
            incl, cnt, bs1, dstptr, cursor, N, Etot);
        scatter_kernel<<<bps * 8, 256, 0, stream>>>(esrc, edst, cursor, ssrc,
                                                    E, N, sliceN, bps);
    }

    const int ggrid = (N + 63) / 64;                   // 64 rows/block (MFMA)
    const int ablocks = (N + 7) / 8;                   // 8 nodes per 256-thr block

    // ---- Layer 1 ----
    gemm_al_kernel<<<ggrid, 256, 0, stream>>>(x, W1, as1, ad1, h16, al, ub, N);
    aggregate_kernel<<<ablocks, 256, 0, stream>>>(h16, al, dstptr, ssrc, ub, b1, y1, N, 0);

    // ---- Layer 2 ----
    gemm_al_kernel<<<ggrid, 256, 0, stream>>>(y1, W2, as2, ad2, h16, al, ub + 2, N);
    aggregate_kernel<<<ablocks, 256, 0, stream>>>(h16, al, dstptr, ssrc, ub + 2, b2, out, N, 1);
}